// Round 1
// baseline (11840.717 us; speedup 1.0000x reference)
//
#include <hip/hip_runtime.h>

#define BB 128
#define NN 512
#define KNNK 4

__device__ __forceinline__ float lrelu(float v) { return v > 0.0f ? v : 0.01f * v; }

// ---------------------------------------------------------------- kNN
// grid: B blocks, 512 threads. feat row stride = ldf, positions = first 3 ch.
__global__ __launch_bounds__(512)
void knn_kernel(const float* __restrict__ feat, int ldf, int* __restrict__ idx_out) {
    __shared__ float px[NN], py[NN], pz[NN], sq[NN];
    const int b = blockIdx.x;
    const int i = threadIdx.x;
    const float* fb = feat + (size_t)b * NN * ldf;
    const float x = fb[(size_t)i * ldf + 0];
    const float y = fb[(size_t)i * ldf + 1];
    const float z = fb[(size_t)i * ldf + 2];
    px[i] = x; py[i] = y; pz[i] = z;
    const float s = x * x + y * y + z * z;
    sq[i] = s;
    __syncthreads();
    float bd0 = 3.4e38f, bd1 = 3.4e38f, bd2 = 3.4e38f, bd3 = 3.4e38f;
    int bj0 = 0, bj1 = 0, bj2 = 0, bj3 = 0;
    for (int j = 0; j < NN; j++) {
        const float d2 = s + sq[j] - 2.0f * (x * px[j] + y * py[j] + z * pz[j]);
        // strict < everywhere -> on exact ties keep the earlier j (top_k semantics)
        if (j != i && d2 < bd3) {
            if (d2 < bd2) {
                bd3 = bd2; bj3 = bj2;
                if (d2 < bd1) {
                    bd2 = bd1; bj2 = bj1;
                    if (d2 < bd0) { bd1 = bd0; bj1 = bj0; bd0 = d2; bj0 = j; }
                    else { bd1 = d2; bj1 = j; }
                } else { bd2 = d2; bj2 = j; }
            } else { bd3 = d2; bj3 = j; }
        }
    }
    int* ip = idx_out + ((size_t)b * NN + i) * KNNK;
    ip[0] = bj0; ip[1] = bj1; ip[2] = bj2; ip[3] = bj3;
}

// ---------------------------------------------------------------- conv1
// FIN=4 (E2=8), HID=96, OUT=192. 16 nodes (64 edges)/block. grid = B*32.
__global__ __launch_bounds__(256, 2)
void conv1_kernel(const float* __restrict__ X,      // [B][N][4]
                  const int* __restrict__ nidx,     // [B][N][4]
                  const float* __restrict__ W1, const float* __restrict__ b1, // [8][96],[96]
                  const float* __restrict__ W2, const float* __restrict__ b2, // [96][192],[192]
                  float* __restrict__ out)          // [B][N][192]
{
    __shared__ float E[8][64];
    __shared__ float W1s[8][96];
    __shared__ float h1t[96][64];
    __shared__ float W2t[32][192];
    __shared__ float b1s[96], b2s[192];

    const int t = threadIdx.x;
    const int b = blockIdx.x >> 5;
    const int nb = (blockIdx.x & 31) << 4;
    const float* Xb = X + (size_t)b * NN * 4;

    for (int i = t; i < 8 * 96; i += 256) W1s[i / 96][i % 96] = W1[i];
    if (t < 96) b1s[t] = b1[t];
    if (t < 192) b2s[t] = b2[t];

    if (t < 64) {
        const int e = t;
        const int node = nb + (e >> 2);
        const int j = nidx[((size_t)b * NN + node) * KNNK + (e & 3)];
        const float4 xi = *(const float4*)(Xb + (size_t)node * 4);
        const float4 xj = *(const float4*)(Xb + (size_t)j * 4);
        E[0][e] = xi.x; E[1][e] = xi.y; E[2][e] = xi.z; E[3][e] = xi.w;
        E[4][e] = xj.x - xi.x; E[5][e] = xj.y - xi.y; E[6][e] = xj.z - xi.z; E[7][e] = xj.w - xi.w;
    }
    __syncthreads();

    const int rg = t & 15;   // 4 rows each (rows = edges; node rg owns rows rg*4..+3)
    {   // GEMM1: 64x8 @ 8x96 -> h1t (leaky)
        const int cg = t >> 4;    // 16 groups x 6 cols
        float acc[4][6];
#pragma unroll
        for (int r = 0; r < 4; r++)
#pragma unroll
            for (int c = 0; c < 6; c++) acc[r][c] = 0.0f;
#pragma unroll
        for (int k = 0; k < 8; k++) {
            const float4 e4 = *(const float4*)&E[k][rg * 4];
            const float er[4] = {e4.x, e4.y, e4.z, e4.w};
            float wc[6];
#pragma unroll
            for (int c = 0; c < 6; c++) wc[c] = W1s[k][cg * 6 + c];
#pragma unroll
            for (int r = 0; r < 4; r++)
#pragma unroll
                for (int c = 0; c < 6; c++) acc[r][c] += er[r] * wc[c];
        }
#pragma unroll
        for (int c = 0; c < 6; c++) {
            const int col = cg * 6 + c;
            const float bias = b1s[col];
#pragma unroll
            for (int r = 0; r < 4; r++) h1t[col][rg * 4 + r] = lrelu(acc[r][c] + bias);
        }
    }
    __syncthreads();

    {   // GEMM2: 64x96 @ 96x192 (+bias, leaky, neighbor-sum) -> out
        const int cg = t >> 4;    // 16 groups x 12 cols
        float acc[4][12];
#pragma unroll
        for (int r = 0; r < 4; r++)
#pragma unroll
            for (int c = 0; c < 12; c++) acc[r][c] = 0.0f;
        for (int kt = 0; kt < 3; kt++) {
            for (int i = t; i < 32 * 192; i += 256)
                W2t[i / 192][i % 192] = W2[(size_t)(kt * 32 + i / 192) * 192 + i % 192];
            __syncthreads();
#pragma unroll
            for (int kk = 0; kk < 32; kk++) {
                const int k = kt * 32 + kk;
                const float4 e4 = *(const float4*)&h1t[k][rg * 4];
                const float er[4] = {e4.x, e4.y, e4.z, e4.w};
                float wc[12];
#pragma unroll
                for (int c = 0; c < 12; c += 4) {
                    const float4 w4 = *(const float4*)&W2t[kk][cg * 12 + c];
                    wc[c] = w4.x; wc[c + 1] = w4.y; wc[c + 2] = w4.z; wc[c + 3] = w4.w;
                }
#pragma unroll
                for (int r = 0; r < 4; r++)
#pragma unroll
                    for (int c = 0; c < 12; c++) acc[r][c] += er[r] * wc[c];
            }
            __syncthreads();
        }
        const int node = nb + rg;
        float res[12];
#pragma unroll
        for (int c = 0; c < 12; c++) {
            const float bias = b2s[cg * 12 + c];
            res[c] = lrelu(acc[0][c] + bias) + lrelu(acc[1][c] + bias)
                   + lrelu(acc[2][c] + bias) + lrelu(acc[3][c] + bias);
        }
        float* op = out + ((size_t)b * NN + node) * 192 + cg * 12;
#pragma unroll
        for (int c = 0; c < 12; c += 4) {
            float4 o; o.x = res[c]; o.y = res[c + 1]; o.z = res[c + 2]; o.w = res[c + 3];
            *(float4*)(op + c) = o;
        }
    }
}

// ---------------------------------------------------------------- conv2/3/4
// F=192 (E2=384), HID=252(pad256), OUT=192. 4 nodes (16 edges)/block. grid = B*128.
__global__ __launch_bounds__(256, 2)
void conv234_kernel(const float* __restrict__ X,     // [B][N][192]
                    const int* __restrict__ nidx,
                    const float* __restrict__ W1,    // [384][252]
                    const float* __restrict__ b1,    // [252]
                    const float* __restrict__ W2,    // [252][192]
                    const float* __restrict__ b2,    // [192]
                    float* __restrict__ out)         // [B][N][192]
{
    __shared__ float E[384][16];
    __shared__ float Wt[16][256];      // W1 tiles; reused flat as [16][192] for W2
    __shared__ float h1t[256][16];
    __shared__ float b1s[256], b2s[192];

    const int t = threadIdx.x;
    const int b = blockIdx.x >> 7;
    const int nb = (blockIdx.x & 127) << 2;
    const float* Xb = X + (size_t)b * NN * 192;

    b1s[t] = (t < 252) ? b1[t] : 0.0f;
    if (t < 192) b2s[t] = b2[t];

    {   // build E (transposed [k][edge])
        const int e = t & 15;
        const int c = t >> 4;   // 16 chunks x 12 floats
        const int node = nb + (e >> 2);
        const int j = nidx[((size_t)b * NN + node) * KNNK + (e & 3)];
        const float* xi = Xb + (size_t)node * 192 + c * 12;
        const float* xj = Xb + (size_t)j * 192 + c * 12;
#pragma unroll
        for (int u = 0; u < 12; u++) {
            const float av = xi[u];
            E[c * 12 + u][e] = av;
            E[192 + c * 12 + u][e] = xj[u] - av;
        }
    }
    __syncthreads();

    const int rg = t & 3;    // 4 rows each (rows = edges; node rg owns rows rg*4..+3)
    const int cg = t >> 2;   // 64 col-groups of 4

    {   // GEMM1: 16x384 @ 384x252(pad256) -> h1t (leaky)
        float acc[4][4];
#pragma unroll
        for (int r = 0; r < 4; r++)
#pragma unroll
            for (int c = 0; c < 4; c++) acc[r][c] = 0.0f;
        for (int kt = 0; kt < 24; kt++) {
            for (int i = t; i < 16 * 256; i += 256) {
                const int kk = i >> 8, c = i & 255;
                Wt[kk][c] = (c < 252) ? W1[(size_t)(kt * 16 + kk) * 252 + c] : 0.0f;
            }
            __syncthreads();
#pragma unroll
            for (int kk = 0; kk < 16; kk++) {
                const float4 e4 = *(const float4*)&E[kt * 16 + kk][rg * 4];
                const float4 w4 = *(const float4*)&Wt[kk][cg * 4];
                const float er[4] = {e4.x, e4.y, e4.z, e4.w};
                const float wc[4] = {w4.x, w4.y, w4.z, w4.w};
#pragma unroll
                for (int r = 0; r < 4; r++)
#pragma unroll
                    for (int c = 0; c < 4; c++) acc[r][c] += er[r] * wc[c];
            }
            __syncthreads();
        }
#pragma unroll
        for (int c = 0; c < 4; c++) {
            const int col = cg * 4 + c;
            const float bias = b1s[col];
#pragma unroll
            for (int r = 0; r < 4; r++) h1t[col][rg * 4 + r] = lrelu(acc[r][c] + bias);
        }
    }
    __syncthreads();

    {   // GEMM2: 16x252 @ 252x192 (+bias, leaky, neighbor-sum) -> out
        float acc[4][4];
#pragma unroll
        for (int r = 0; r < 4; r++)
#pragma unroll
            for (int c = 0; c < 4; c++) acc[r][c] = 0.0f;
        const bool act = (cg < 48);
        float* Wf = (float*)Wt;
        for (int kt = 0; kt < 16; kt++) {
            for (int i = t; i < 16 * 192; i += 256) {
                const int kk = i / 192, c = i % 192;
                const int krow = kt * 16 + kk;
                Wf[kk * 192 + c] = (krow < 252) ? W2[(size_t)krow * 192 + c] : 0.0f;
            }
            __syncthreads();
            if (act) {
#pragma unroll
                for (int kk = 0; kk < 16; kk++) {
                    const float4 e4 = *(const float4*)&h1t[kt * 16 + kk][rg * 4];
                    const float4 w4 = *(const float4*)&Wf[kk * 192 + cg * 4];
                    const float er[4] = {e4.x, e4.y, e4.z, e4.w};
                    const float wc[4] = {w4.x, w4.y, w4.z, w4.w};
#pragma unroll
                    for (int r = 0; r < 4; r++)
#pragma unroll
                        for (int c = 0; c < 4; c++) acc[r][c] += er[r] * wc[c];
                }
            }
            __syncthreads();
        }
        if (act) {
            const int node = nb + rg;
            float res[4];
#pragma unroll
            for (int c = 0; c < 4; c++) {
                const float bias = b2s[cg * 4 + c];
                res[c] = lrelu(acc[0][c] + bias) + lrelu(acc[1][c] + bias)
                       + lrelu(acc[2][c] + bias) + lrelu(acc[3][c] + bias);
            }
            float4 o; o.x = res[0]; o.y = res[1]; o.z = res[2]; o.w = res[3];
            *(float4*)(out + ((size_t)b * NN + node) * 192 + cg * 4) = o;
        }
    }
}

// ---------------------------------------------------------------- nn1+nn2+block pool
// 16 nodes/block, grid = B*32. partials: [B][32][3][192] (max,min,sum)
__global__ __launch_bounds__(256, 2)
void nn12_kernel(const float* __restrict__ x,
                 const float* __restrict__ a,
                 const float* __restrict__ bbf,
                 const float* __restrict__ cbf,
                 const float* __restrict__ dbf,
                 const float* __restrict__ W1, const float* __restrict__ b1, // [772][252]
                 const float* __restrict__ W2, const float* __restrict__ b2, // [252][192]
                 float* __restrict__ partials)
{
    __shared__ float Xt[16][16];
    __shared__ float Wt[16][256];
    __shared__ float h1t[256][16];
    __shared__ float h2s[16][192];
    __shared__ float b1s[256], b2s[192];

    const int t = threadIdx.x;
    const int b = blockIdx.x >> 5;
    const int blkl = blockIdx.x & 31;
    const int nb = blkl << 4;

    b1s[t] = (t < 252) ? b1[t] : 0.0f;
    if (t < 192) b2s[t] = b2[t];

    const int rg = t & 3, cg = t >> 2;

    float acc[4][4];
#pragma unroll
    for (int r = 0; r < 4; r++)
#pragma unroll
        for (int c = 0; c < 4; c++) acc[r][c] = 0.0f;

    const float* srcs[5] = {x, a, bbf, cbf, dbf};
    const int nks[5] = {4, 192, 192, 192, 192};
    const int koffs[5] = {0, 4, 196, 388, 580};
#pragma unroll
    for (int s = 0; s < 5; s++) {
        const float* sp = srcs[s] + (size_t)b * NN * nks[s];
        const int nk = nks[s];
        for (int k0 = 0; k0 < nk; k0 += 16) {
            const int rows = (nk - k0 < 16) ? (nk - k0) : 16;
            if (rows == 16) {
                const int kk = t & 15, node = t >> 4;
                Xt[kk][node] = sp[(size_t)(nb + node) * nk + k0 + kk];
            } else if (t < rows * 16) {
                const int kk = t % rows, node = t / rows;
                Xt[kk][node] = sp[(size_t)(nb + node) * nk + k0 + kk];
            }
            for (int i = t; i < rows * 256; i += 256) {
                const int kk = i >> 8, c = i & 255;
                Wt[kk][c] = (c < 252) ? W1[(size_t)(koffs[s] + k0 + kk) * 252 + c] : 0.0f;
            }
            __syncthreads();
            for (int kk = 0; kk < rows; kk++) {
                const float4 e4 = *(const float4*)&Xt[kk][rg * 4];
                const float4 w4 = *(const float4*)&Wt[kk][cg * 4];
                const float er[4] = {e4.x, e4.y, e4.z, e4.w};
                const float wc[4] = {w4.x, w4.y, w4.z, w4.w};
#pragma unroll
                for (int r = 0; r < 4; r++)
#pragma unroll
                    for (int c = 0; c < 4; c++) acc[r][c] += er[r] * wc[c];
            }
            __syncthreads();
        }
    }
#pragma unroll
    for (int c = 0; c < 4; c++) {
        const int col = cg * 4 + c;
        const float bias = b1s[col];
#pragma unroll
        for (int r = 0; r < 4; r++) h1t[col][rg * 4 + r] = lrelu(acc[r][c] + bias);
    }
    __syncthreads();

    {   // GEMM2 (no activation) -> h2s
        float acc2[4][4];
#pragma unroll
        for (int r = 0; r < 4; r++)
#pragma unroll
            for (int c = 0; c < 4; c++) acc2[r][c] = 0.0f;
        const bool act = (cg < 48);
        float* Wf = (float*)Wt;
        for (int kt = 0; kt < 16; kt++) {
            for (int i = t; i < 16 * 192; i += 256) {
                const int kk = i / 192, c = i % 192;
                const int krow = kt * 16 + kk;
                Wf[kk * 192 + c] = (krow < 252) ? W2[(size_t)krow * 192 + c] : 0.0f;
            }
            __syncthreads();
            if (act) {
#pragma unroll
                for (int kk = 0; kk < 16; kk++) {
                    const float4 e4 = *(const float4*)&h1t[kt * 16 + kk][rg * 4];
                    const float4 w4 = *(const float4*)&Wf[kk * 192 + cg * 4];
                    const float er[4] = {e4.x, e4.y, e4.z, e4.w};
                    const float wc[4] = {w4.x, w4.y, w4.z, w4.w};
#pragma unroll
                    for (int r = 0; r < 4; r++)
#pragma unroll
                        for (int c = 0; c < 4; c++) acc2[r][c] += er[r] * wc[c];
                }
            }
            __syncthreads();
        }
        if (act) {
#pragma unroll
            for (int c = 0; c < 4; c++) {
                const int col = cg * 4 + c;
                const float bias = b2s[col];
#pragma unroll
                for (int r = 0; r < 4; r++) h2s[rg * 4 + r][col] = acc2[r][c] + bias;
            }
        }
    }
    __syncthreads();
    if (t < 192) {
        float mx = -3.4e38f, mn = 3.4e38f, sm = 0.0f;
#pragma unroll 4
        for (int n = 0; n < 16; n++) {
            const float v = h2s[n][t];
            mx = fmaxf(mx, v); mn = fminf(mn, v); sm += v;
        }
        float* pp = partials + ((size_t)b * 32 + blkl) * 3 * 192;
        pp[t] = mx; pp[192 + t] = mn; pp[384 + t] = sm;
    }
}

// ---------------------------------------------------------------- pool reduce
// grid B, 192 threads. pooledL[b][768] = leaky([max|min|sum|mean])
__global__ void pool_reduce_kernel(const float* __restrict__ partials, float* __restrict__ pooledL) {
    const int b = blockIdx.x, c = threadIdx.x;
    float mx = -3.4e38f, mn = 3.4e38f, sm = 0.0f;
    for (int blk = 0; blk < 32; blk++) {
        const float* pp = partials + ((size_t)b * 32 + blk) * 3 * 192;
        mx = fmaxf(mx, pp[c]);
        mn = fminf(mn, pp[192 + c]);
        sm += pp[384 + c];
    }
    float* o = pooledL + (size_t)b * 768;
    o[c] = lrelu(mx);
    o[192 + c] = lrelu(mn);
    o[384 + c] = lrelu(sm);
    o[576 + c] = lrelu(sm * (1.0f / 512.0f));
}

// ---------------------------------------------------------------- head
// grid B, 128 threads
__global__ __launch_bounds__(128)
void head_kernel(const float* __restrict__ pooledL,
                 const float* __restrict__ W3, const float* __restrict__ b3, // [768][96],[96]
                 const float* __restrict__ W4, const float* __restrict__ b4, // [96][1],[1]
                 float* __restrict__ out) {
    __shared__ float pl[768];
    __shared__ float h3[96];
    const int b = blockIdx.x, t = threadIdx.x;
    for (int i = t; i < 768; i += 128) pl[i] = pooledL[(size_t)b * 768 + i];
    __syncthreads();
    if (t < 96) {
        float acc = b3[t];
        for (int k = 0; k < 768; k++) acc += pl[k] * W3[(size_t)k * 96 + t];
        h3[t] = lrelu(acc);
    }
    __syncthreads();
    if (t == 0) {
        float s2 = b4[0];
        for (int o = 0; o < 96; o++) s2 += h3[o] * W4[o];
        out[b] = s2;
    }
}

// ---------------------------------------------------------------- launch
extern "C" void kernel_launch(void* const* d_in, const int* in_sizes, int n_in,
                              void* d_out, int out_size, void* d_ws, size_t ws_size,
                              hipStream_t stream) {
    const float* x    = (const float*)d_in[0];
    const float* c1w1 = (const float*)d_in[1];
    const float* c1b1 = (const float*)d_in[2];
    const float* c1w2 = (const float*)d_in[3];
    const float* c1b2 = (const float*)d_in[4];
    const float* c2w1 = (const float*)d_in[5];
    const float* c2b1 = (const float*)d_in[6];
    const float* c2w2 = (const float*)d_in[7];
    const float* c2b2 = (const float*)d_in[8];
    const float* c3w1 = (const float*)d_in[9];
    const float* c3b1 = (const float*)d_in[10];
    const float* c3w2 = (const float*)d_in[11];
    const float* c3b2 = (const float*)d_in[12];
    const float* c4w1 = (const float*)d_in[13];
    const float* c4b1 = (const float*)d_in[14];
    const float* c4w2 = (const float*)d_in[15];
    const float* c4b2 = (const float*)d_in[16];
    const float* nn1w = (const float*)d_in[17];
    const float* nn1b = (const float*)d_in[18];
    const float* nn2w = (const float*)d_in[19];
    const float* nn2b = (const float*)d_in[20];
    const float* nn3w = (const float*)d_in[21];
    const float* nn3b = (const float*)d_in[22];
    const float* nn4w = (const float*)d_in[23];
    const float* nn4b = (const float*)d_in[24];
    float* out = (float*)d_out;

    // workspace layout (needs ~212.3 MB)
    const size_t featN = (size_t)BB * NN * 192;
    float* abuf = (float*)d_ws;
    float* bbuf = abuf + featN;
    float* cbuf = bbuf + featN;
    float* dbuf = cbuf + featN;
    int* idxb = (int*)(dbuf + featN);
    float* partials = (float*)(idxb + (size_t)BB * NN * KNNK);
    float* pooledL = partials + (size_t)BB * 32 * 3 * 192;

    knn_kernel<<<BB, 512, 0, stream>>>(x, 4, idxb);
    conv1_kernel<<<BB * 32, 256, 0, stream>>>(x, idxb, c1w1, c1b1, c1w2, c1b2, abuf);
    knn_kernel<<<BB, 512, 0, stream>>>(abuf, 192, idxb);
    conv234_kernel<<<BB * 128, 256, 0, stream>>>(abuf, idxb, c2w1, c2b1, c2w2, c2b2, bbuf);
    knn_kernel<<<BB, 512, 0, stream>>>(bbuf, 192, idxb);
    conv234_kernel<<<BB * 128, 256, 0, stream>>>(bbuf, idxb, c3w1, c3b1, c3w2, c3b2, cbuf);
    knn_kernel<<<BB, 512, 0, stream>>>(cbuf, 192, idxb);
    conv234_kernel<<<BB * 128, 256, 0, stream>>>(cbuf, idxb, c4w1, c4b1, c4w2, c4b2, dbuf);
    nn12_kernel<<<BB * 32, 256, 0, stream>>>(x, abuf, bbuf, cbuf, dbuf, nn1w, nn1b, nn2w, nn2b, partials);
    pool_reduce_kernel<<<BB, 192, 0, stream>>>(partials, pooledL);
    head_kernel<<<BB, 128, 0, stream>>>(pooledL, nn3w, nn3b, nn4w, nn4b, out);
}

// Round 2
// 3961.075 us; speedup vs baseline: 2.9893x; 2.9893x over previous
//
#include <hip/hip_runtime.h>

#define BB 128
#define NN 512
#define KNNK 4

__device__ __forceinline__ float lrelu(float v) { return v > 0.0f ? v : 0.01f * v; }

// ---------------------------------------------------------------- kNN
__global__ __launch_bounds__(512)
void knn_kernel(const float* __restrict__ feat, int ldf, int* __restrict__ idx_out) {
    __shared__ float px[NN], py[NN], pz[NN], sq[NN];
    const int b = blockIdx.x;
    const int i = threadIdx.x;
    const float* fb = feat + (size_t)b * NN * ldf;
    const float x = fb[(size_t)i * ldf + 0];
    const float y = fb[(size_t)i * ldf + 1];
    const float z = fb[(size_t)i * ldf + 2];
    px[i] = x; py[i] = y; pz[i] = z;
    const float s = x * x + y * y + z * z;
    sq[i] = s;
    __syncthreads();
    float bd0 = 3.4e38f, bd1 = 3.4e38f, bd2 = 3.4e38f, bd3 = 3.4e38f;
    int bj0 = 0, bj1 = 0, bj2 = 0, bj3 = 0;
    for (int j = 0; j < NN; j++) {
        const float d2 = s + sq[j] - 2.0f * (x * px[j] + y * py[j] + z * pz[j]);
        if (j != i && d2 < bd3) {
            if (d2 < bd2) {
                bd3 = bd2; bj3 = bj2;
                if (d2 < bd1) {
                    bd2 = bd1; bj2 = bj1;
                    if (d2 < bd0) { bd1 = bd0; bj1 = bj0; bd0 = d2; bj0 = j; }
                    else { bd1 = d2; bj1 = j; }
                } else { bd2 = d2; bj2 = j; }
            } else { bd3 = d2; bj3 = j; }
        }
    }
    int* ip = idx_out + ((size_t)b * NN + i) * KNNK;
    ip[0] = bj0; ip[1] = bj1; ip[2] = bj2; ip[3] = bj3;
}

// ---------------------------------------------------------------- conv1 (unchanged)
__global__ __launch_bounds__(256, 2)
void conv1_kernel(const float* __restrict__ X,
                  const int* __restrict__ nidx,
                  const float* __restrict__ W1, const float* __restrict__ b1,
                  const float* __restrict__ W2, const float* __restrict__ b2,
                  float* __restrict__ out)
{
    __shared__ float E[8][64];
    __shared__ float W1s[8][96];
    __shared__ float h1t[96][64];
    __shared__ float W2t[32][192];
    __shared__ float b1s[96], b2s[192];

    const int t = threadIdx.x;
    const int b = blockIdx.x >> 5;
    const int nb = (blockIdx.x & 31) << 4;
    const float* Xb = X + (size_t)b * NN * 4;

    for (int i = t; i < 8 * 96; i += 256) W1s[i / 96][i % 96] = W1[i];
    if (t < 96) b1s[t] = b1[t];
    if (t < 192) b2s[t] = b2[t];

    if (t < 64) {
        const int e = t;
        const int node = nb + (e >> 2);
        const int j = nidx[((size_t)b * NN + node) * KNNK + (e & 3)];
        const float4 xi = *(const float4*)(Xb + (size_t)node * 4);
        const float4 xj = *(const float4*)(Xb + (size_t)j * 4);
        E[0][e] = xi.x; E[1][e] = xi.y; E[2][e] = xi.z; E[3][e] = xi.w;
        E[4][e] = xj.x - xi.x; E[5][e] = xj.y - xi.y; E[6][e] = xj.z - xi.z; E[7][e] = xj.w - xi.w;
    }
    __syncthreads();

    const int rg = t & 15;
    {   // GEMM1
        const int cg = t >> 4;
        float acc[4][6];
#pragma unroll
        for (int r = 0; r < 4; r++)
#pragma unroll
            for (int c = 0; c < 6; c++) acc[r][c] = 0.0f;
#pragma unroll
        for (int k = 0; k < 8; k++) {
            const float4 e4 = *(const float4*)&E[k][rg * 4];
            const float er[4] = {e4.x, e4.y, e4.z, e4.w};
            float wc[6];
#pragma unroll
            for (int c = 0; c < 6; c++) wc[c] = W1s[k][cg * 6 + c];
#pragma unroll
            for (int r = 0; r < 4; r++)
#pragma unroll
                for (int c = 0; c < 6; c++) acc[r][c] += er[r] * wc[c];
        }
#pragma unroll
        for (int c = 0; c < 6; c++) {
            const int col = cg * 6 + c;
            const float bias = b1s[col];
#pragma unroll
            for (int r = 0; r < 4; r++) h1t[col][rg * 4 + r] = lrelu(acc[r][c] + bias);
        }
    }
    __syncthreads();

    {   // GEMM2
        const int cg = t >> 4;
        float acc[4][12];
#pragma unroll
        for (int r = 0; r < 4; r++)
#pragma unroll
            for (int c = 0; c < 12; c++) acc[r][c] = 0.0f;
        for (int kt = 0; kt < 3; kt++) {
            for (int i = t; i < 32 * 192; i += 256)
                W2t[i / 192][i % 192] = W2[(size_t)(kt * 32 + i / 192) * 192 + i % 192];
            __syncthreads();
#pragma unroll
            for (int kk = 0; kk < 32; kk++) {
                const int k = kt * 32 + kk;
                const float4 e4 = *(const float4*)&h1t[k][rg * 4];
                const float er[4] = {e4.x, e4.y, e4.z, e4.w};
                float wc[12];
#pragma unroll
                for (int c = 0; c < 12; c += 4) {
                    const float4 w4 = *(const float4*)&W2t[kk][cg * 12 + c];
                    wc[c] = w4.x; wc[c + 1] = w4.y; wc[c + 2] = w4.z; wc[c + 3] = w4.w;
                }
#pragma unroll
                for (int r = 0; r < 4; r++)
#pragma unroll
                    for (int c = 0; c < 12; c++) acc[r][c] += er[r] * wc[c];
            }
            __syncthreads();
        }
        const int node = nb + rg;
        float res[12];
#pragma unroll
        for (int c = 0; c < 12; c++) {
            const float bias = b2s[cg * 12 + c];
            res[c] = lrelu(acc[0][c] + bias) + lrelu(acc[1][c] + bias)
                   + lrelu(acc[2][c] + bias) + lrelu(acc[3][c] + bias);
        }
        float* op = out + ((size_t)b * NN + node) * 192 + cg * 12;
#pragma unroll
        for (int c = 0; c < 12; c += 4) {
            float4 o; o.x = res[c]; o.y = res[c + 1]; o.z = res[c + 2]; o.w = res[c + 3];
            *(float4*)(op + c) = o;
        }
    }
}

// ---------------------------------------------------------------- weight prep
// Wcat[192][512]: cols 0..251 = W1[0:192]-W1[192:384]; 256..507 = W1[192:384]; else 0
__global__ void wprep_kernel(const float* __restrict__ W1, float* __restrict__ Wcat) {
    const int idx = blockIdx.x * 256 + threadIdx.x;   // 192*512
    const int k = idx >> 9;
    const int c = idx & 511;
    float v = 0.0f;
    if (c < 252) v = W1[(size_t)k * 252 + c] - W1[(size_t)(192 + k) * 252 + c];
    else if (c >= 256 && c < 508) v = W1[(size_t)(192 + k) * 252 + (c - 256)];
    Wcat[idx] = v;
}

// ---------------------------------------------------------------- PQ node GEMM
// PQ[rows][512] = X[rows][192] @ Wcat[192][512]. rows = CB*512. grid = rows/64 * 4.
__global__ __launch_bounds__(256, 4)
void pq_gemm_kernel(const float* __restrict__ X,
                    const float* __restrict__ Wcat,
                    float* __restrict__ PQ)
{
    __shared__ float Xt[16][68];   // [k][node], padded
    __shared__ float Wt[16][128];
    const int t = threadIdx.x;
    const int m0 = (blockIdx.x >> 2) << 6;
    const int n0 = (blockIdx.x & 3) << 7;

    const int rg = t & 15, cg = t >> 4;
    const int sm = t >> 2;            // staging node 0..63
    const int skq = (t & 3) << 2;     // staging k 0,4,8,12

    // hoisted W-stage indices
    const int q0 = t, q1 = t + 256;
    const int kkA = q0 >> 5, c4A = (q0 & 31) << 2;
    const int kkB = q1 >> 5, c4B = (q1 & 31) << 2;

    float acc[4][8];
#pragma unroll
    for (int r = 0; r < 4; r++)
#pragma unroll
        for (int c = 0; c < 8; c++) acc[r][c] = 0.0f;

    for (int kt = 0; kt < 12; ++kt) {
        const int k0 = kt << 4;
        const float4 xv = *(const float4*)&X[(size_t)(m0 + sm) * 192 + k0 + skq];
        Xt[skq + 0][sm] = xv.x;
        Xt[skq + 1][sm] = xv.y;
        Xt[skq + 2][sm] = xv.z;
        Xt[skq + 3][sm] = xv.w;
        *(float4*)&Wt[kkA][c4A] = *(const float4*)&Wcat[(size_t)(k0 + kkA) * 512 + n0 + c4A];
        *(float4*)&Wt[kkB][c4B] = *(const float4*)&Wcat[(size_t)(k0 + kkB) * 512 + n0 + c4B];
        __syncthreads();
#pragma unroll
        for (int kk = 0; kk < 16; ++kk) {
            const float4 x4 = *(const float4*)&Xt[kk][rg * 4];
            const float4 w0 = *(const float4*)&Wt[kk][cg * 8];
            const float4 w1 = *(const float4*)&Wt[kk][cg * 8 + 4];
            const float xr[4] = {x4.x, x4.y, x4.z, x4.w};
            const float wc[8] = {w0.x, w0.y, w0.z, w0.w, w1.x, w1.y, w1.z, w1.w};
#pragma unroll
            for (int r = 0; r < 4; r++)
#pragma unroll
                for (int c = 0; c < 8; c++) acc[r][c] += xr[r] * wc[c];
        }
        __syncthreads();
    }
#pragma unroll
    for (int r = 0; r < 4; r++) {
        float* op = PQ + (size_t)(m0 + rg * 4 + r) * 512 + n0 + cg * 8;
        float4 o0; o0.x = acc[r][0]; o0.y = acc[r][1]; o0.z = acc[r][2]; o0.w = acc[r][3];
        float4 o1; o1.x = acc[r][4]; o1.y = acc[r][5]; o1.z = acc[r][6]; o1.w = acc[r][7];
        *(float4*)op = o0;
        *(float4*)(op + 4) = o1;
    }
}

// ---------------------------------------------------------------- conv2/3/4 edge phase
// h1_edge = lrelu(P_i + Q_j + b1); out_i = sum_j lrelu(h1 @ W2 + b2).
// 16 nodes (64 edges)/block, 256 threads. grid = CB*32.
__global__ __launch_bounds__(256, 4)
void conv234e_kernel(const float* __restrict__ PQ,    // [CB*512][512]
                     const int* __restrict__ nidx,    // [CB*512][4]
                     const float* __restrict__ W2,    // [252][192]
                     const float* __restrict__ b1,    // [252]
                     const float* __restrict__ b2,    // [192]
                     float* __restrict__ out)         // [CB*512][192]
{
    __shared__ float h1c[16][64];    // [k][edge]
    __shared__ float Wt[16][192];
    __shared__ float b1s[256];
    __shared__ float b2s[192];

    const int t = threadIdx.x;
    const int nodebase = (blockIdx.x >> 5) << 9;
    const int nb = (blockIdx.x & 31) << 4;

    b1s[t] = (t < 252) ? b1[t] : 0.0f;
    if (t < 192) b2s[t] = b2[t];

    const int m = t & 15;     // node within block (both staging + compute row role)
    const int ks = t >> 4;    // staging k-offset / compute col-group

    const int4 jj = *(const int4*)&nidx[(size_t)(nodebase + nb + m) * 4];
    const float* Prow = PQ + (size_t)(nodebase + nb + m) * 512;
    const float* Q0 = PQ + (size_t)(nodebase + jj.x) * 512 + 256;
    const float* Q1 = PQ + (size_t)(nodebase + jj.y) * 512 + 256;
    const float* Q2 = PQ + (size_t)(nodebase + jj.z) * 512 + 256;
    const float* Q3 = PQ + (size_t)(nodebase + jj.w) * 512 + 256;

    // hoisted W2-stage indices (3 float4 per thread)
    const int qa = t, qb = t + 256, qc = t + 512;
    const int kka = qa / 48, ca = (qa % 48) << 2;
    const int kkb = qb / 48, cb = (qb % 48) << 2;
    const int kkc = qc / 48, cc = (qc % 48) << 2;

    float acc[4][12];
#pragma unroll
    for (int r = 0; r < 4; r++)
#pragma unroll
        for (int c = 0; c < 12; c++) acc[r][c] = 0.0f;

    __syncthreads();   // b1s/b2s ready

    const float4 zero4 = {0.0f, 0.0f, 0.0f, 0.0f};
    for (int kt = 0; kt < 16; ++kt) {
        const int k0 = kt << 4;
        {   // h1 chunk: this thread covers k = k0+ks for all 4 edges of node m
            const int k = k0 + ks;
            const float pv = Prow[k] + b1s[k];
            float4 h;
            h.x = lrelu(pv + Q0[k]);
            h.y = lrelu(pv + Q1[k]);
            h.z = lrelu(pv + Q2[k]);
            h.w = lrelu(pv + Q3[k]);
            *(float4*)&h1c[ks][m * 4] = h;
        }
        {   // W2 tile (rows >= 252 are zero)
            const int ra = k0 + kka, rb = k0 + kkb, rc = k0 + kkc;
            *(float4*)&Wt[kka][ca] = (ra < 252) ? *(const float4*)&W2[(size_t)ra * 192 + ca] : zero4;
            *(float4*)&Wt[kkb][cb] = (rb < 252) ? *(const float4*)&W2[(size_t)rb * 192 + cb] : zero4;
            *(float4*)&Wt[kkc][cc] = (rc < 252) ? *(const float4*)&W2[(size_t)rc * 192 + cc] : zero4;
        }
        __syncthreads();
#pragma unroll
        for (int kk = 0; kk < 16; ++kk) {
            const float4 h4 = *(const float4*)&h1c[kk][m * 4];
            const float4 w0 = *(const float4*)&Wt[kk][ks * 12];
            const float4 w1 = *(const float4*)&Wt[kk][ks * 12 + 4];
            const float4 w2 = *(const float4*)&Wt[kk][ks * 12 + 8];
            const float hr[4] = {h4.x, h4.y, h4.z, h4.w};
            const float wc[12] = {w0.x, w0.y, w0.z, w0.w, w1.x, w1.y, w1.z, w1.w, w2.x, w2.y, w2.z, w2.w};
#pragma unroll
            for (int r = 0; r < 4; r++)
#pragma unroll
                for (int c = 0; c < 12; c++) acc[r][c] += hr[r] * wc[c];
        }
        __syncthreads();
    }
    // epilogue: bias + lrelu + neighbor-sum; node m, cols ks*12..+11
    float res[12];
#pragma unroll
    for (int c = 0; c < 12; c++) {
        const float bias = b2s[ks * 12 + c];
        res[c] = lrelu(acc[0][c] + bias) + lrelu(acc[1][c] + bias)
               + lrelu(acc[2][c] + bias) + lrelu(acc[3][c] + bias);
    }
    float* op = out + (size_t)(nodebase + nb + m) * 192 + ks * 12;
#pragma unroll
    for (int c = 0; c < 12; c += 4) {
        float4 o; o.x = res[c]; o.y = res[c + 1]; o.z = res[c + 2]; o.w = res[c + 3];
        *(float4*)(op + c) = o;
    }
}

// ---------------------------------------------------------------- nn1+nn2+block pool (unchanged)
__global__ __launch_bounds__(256, 2)
void nn12_kernel(const float* __restrict__ x,
                 const float* __restrict__ a,
                 const float* __restrict__ bbf,
                 const float* __restrict__ cbf,
                 const float* __restrict__ dbf,
                 const float* __restrict__ W1, const float* __restrict__ b1,
                 const float* __restrict__ W2, const float* __restrict__ b2,
                 float* __restrict__ partials)
{
    __shared__ float Xt[16][16];
    __shared__ float Wt[16][256];
    __shared__ float h1t[256][16];
    __shared__ float h2s[16][192];
    __shared__ float b1s[256], b2s[192];

    const int t = threadIdx.x;
    const int b = blockIdx.x >> 5;
    const int blkl = blockIdx.x & 31;
    const int nb = blkl << 4;

    b1s[t] = (t < 252) ? b1[t] : 0.0f;
    if (t < 192) b2s[t] = b2[t];

    const int rg = t & 3, cg = t >> 2;

    float acc[4][4];
#pragma unroll
    for (int r = 0; r < 4; r++)
#pragma unroll
        for (int c = 0; c < 4; c++) acc[r][c] = 0.0f;

    const float* srcs[5] = {x, a, bbf, cbf, dbf};
    const int nks[5] = {4, 192, 192, 192, 192};
#pragma unroll
    for (int s = 0; s < 5; s++) {
        const int koffs[5] = {0, 4, 196, 388, 580};
        const float* sp = srcs[s] + (size_t)b * NN * nks[s];
        const int nk = nks[s];
        for (int k0 = 0; k0 < nk; k0 += 16) {
            const int rows = (nk - k0 < 16) ? (nk - k0) : 16;
            if (rows == 16) {
                const int kk = t & 15, node = t >> 4;
                Xt[kk][node] = sp[(size_t)(nb + node) * nk + k0 + kk];
            } else if (t < rows * 16) {
                const int kk = t % rows, node = t / rows;
                Xt[kk][node] = sp[(size_t)(nb + node) * nk + k0 + kk];
            }
            for (int i = t; i < rows * 256; i += 256) {
                const int kk = i >> 8, c = i & 255;
                Wt[kk][c] = (c < 252) ? W1[(size_t)(koffs[s] + k0 + kk) * 252 + c] : 0.0f;
            }
            __syncthreads();
            for (int kk = 0; kk < rows; kk++) {
                const float4 e4 = *(const float4*)&Xt[kk][rg * 4];
                const float4 w4 = *(const float4*)&Wt[kk][cg * 4];
                const float er[4] = {e4.x, e4.y, e4.z, e4.w};
                const float wc[4] = {w4.x, w4.y, w4.z, w4.w};
#pragma unroll
                for (int r = 0; r < 4; r++)
#pragma unroll
                    for (int c = 0; c < 4; c++) acc[r][c] += er[r] * wc[c];
            }
            __syncthreads();
        }
    }
#pragma unroll
    for (int c = 0; c < 4; c++) {
        const int col = cg * 4 + c;
        const float bias = b1s[col];
#pragma unroll
        for (int r = 0; r < 4; r++) h1t[col][rg * 4 + r] = lrelu(acc[r][c] + bias);
    }
    __syncthreads();

    {
        float acc2[4][4];
#pragma unroll
        for (int r = 0; r < 4; r++)
#pragma unroll
            for (int c = 0; c < 4; c++) acc2[r][c] = 0.0f;
        const bool act = (cg < 48);
        float* Wf = (float*)Wt;
        for (int kt = 0; kt < 16; kt++) {
            for (int i = t; i < 16 * 192; i += 256) {
                const int kk = i / 192, c = i % 192;
                const int krow = kt * 16 + kk;
                Wf[kk * 192 + c] = (krow < 252) ? W2[(size_t)krow * 192 + c] : 0.0f;
            }
            __syncthreads();
            if (act) {
#pragma unroll
                for (int kk = 0; kk < 16; kk++) {
                    const float4 e4 = *(const float4*)&h1t[kt * 16 + kk][rg * 4];
                    const float4 w4 = *(const float4*)&Wf[kk * 192 + cg * 4];
                    const float er[4] = {e4.x, e4.y, e4.z, e4.w};
                    const float wc[4] = {w4.x, w4.y, w4.z, w4.w};
#pragma unroll
                    for (int r = 0; r < 4; r++)
#pragma unroll
                        for (int c = 0; c < 4; c++) acc2[r][c] += er[r] * wc[c];
                }
            }
            __syncthreads();
        }
        if (act) {
#pragma unroll
            for (int c = 0; c < 4; c++) {
                const int col = cg * 4 + c;
                const float bias = b2s[col];
#pragma unroll
                for (int r = 0; r < 4; r++) h2s[rg * 4 + r][col] = acc2[r][c] + bias;
            }
        }
    }
    __syncthreads();
    if (t < 192) {
        float mx = -3.4e38f, mn = 3.4e38f, sm = 0.0f;
#pragma unroll 4
        for (int n = 0; n < 16; n++) {
            const float v = h2s[n][t];
            mx = fmaxf(mx, v); mn = fminf(mn, v); sm += v;
        }
        float* pp = partials + ((size_t)b * 32 + blkl) * 3 * 192;
        pp[t] = mx; pp[192 + t] = mn; pp[384 + t] = sm;
    }
}

// ---------------------------------------------------------------- pool reduce
__global__ void pool_reduce_kernel(const float* __restrict__ partials, float* __restrict__ pooledL) {
    const int b = blockIdx.x, c = threadIdx.x;
    float mx = -3.4e38f, mn = 3.4e38f, sm = 0.0f;
    for (int blk = 0; blk < 32; blk++) {
        const float* pp = partials + ((size_t)b * 32 + blk) * 3 * 192;
        mx = fmaxf(mx, pp[c]);
        mn = fminf(mn, pp[192 + c]);
        sm += pp[384 + c];
    }
    float* o = pooledL + (size_t)b * 768;
    o[c] = lrelu(mx);
    o[192 + c] = lrelu(mn);
    o[384 + c] = lrelu(sm);
    o[576 + c] = lrelu(sm * (1.0f / 512.0f));
}

// ---------------------------------------------------------------- head
__global__ __launch_bounds__(128)
void head_kernel(const float* __restrict__ pooledL,
                 const float* __restrict__ W3, const float* __restrict__ b3,
                 const float* __restrict__ W4, const float* __restrict__ b4,
                 float* __restrict__ out) {
    __shared__ float pl[768];
    __shared__ float h3[96];
    const int b = blockIdx.x, t = threadIdx.x;
    for (int i = t; i < 768; i += 128) pl[i] = pooledL[(size_t)b * 768 + i];
    __syncthreads();
    if (t < 96) {
        float acc = b3[t];
        for (int k = 0; k < 768; k++) acc += pl[k] * W3[(size_t)k * 96 + t];
        h3[t] = lrelu(acc);
    }
    __syncthreads();
    if (t == 0) {
        float s2 = b4[0];
        for (int o = 0; o < 96; o++) s2 += h3[o] * W4[o];
        out[b] = s2;
    }
}

// ---------------------------------------------------------------- launch
extern "C" void kernel_launch(void* const* d_in, const int* in_sizes, int n_in,
                              void* d_out, int out_size, void* d_ws, size_t ws_size,
                              hipStream_t stream) {
    const float* x    = (const float*)d_in[0];
    const float* c1w1 = (const float*)d_in[1];
    const float* c1b1 = (const float*)d_in[2];
    const float* c1w2 = (const float*)d_in[3];
    const float* c1b2 = (const float*)d_in[4];
    const float* cw1[3] = {(const float*)d_in[5], (const float*)d_in[9],  (const float*)d_in[13]};
    const float* cb1[3] = {(const float*)d_in[6], (const float*)d_in[10], (const float*)d_in[14]};
    const float* cw2[3] = {(const float*)d_in[7], (const float*)d_in[11], (const float*)d_in[15]};
    const float* cb2[3] = {(const float*)d_in[8], (const float*)d_in[12], (const float*)d_in[16]};
    const float* nn1w = (const float*)d_in[17];
    const float* nn1b = (const float*)d_in[18];
    const float* nn2w = (const float*)d_in[19];
    const float* nn2b = (const float*)d_in[20];
    const float* nn3w = (const float*)d_in[21];
    const float* nn3b = (const float*)d_in[22];
    const float* nn4w = (const float*)d_in[23];
    const float* nn4b = (const float*)d_in[24];
    float* out = (float*)d_out;

    // workspace layout (floats)
    const size_t featN = (size_t)BB * NN * 192;
    const size_t idx_f = (size_t)BB * NN * KNNK;        // ints
    const size_t part_f = (size_t)BB * 32 * 3 * 192;
    const size_t pool_f = (size_t)BB * 768;
    const size_t wcat_f = (size_t)192 * 512;

    float* abuf = (float*)d_ws;
    float* bbuf = abuf + featN;
    float* cbuf = bbuf + featN;
    float* dbuf = cbuf + featN;
    int*   idxb = (int*)(dbuf + featN);
    float* partials = (float*)(idxb + idx_f);
    float* pooledL = partials + part_f;
    float* wcat = pooledL + pool_f;
    float* pqbuf = wcat + wcat_f;

    // pick largest batch-chunk for the PQ buffer that fits ws
    int CB = BB;
    while (CB > 1) {
        const size_t need = (4 * featN + idx_f + part_f + pool_f + wcat_f +
                             (size_t)CB * NN * 512) * 4;
        if (need <= ws_size) break;
        CB >>= 1;
    }
    const int nchunks = BB / CB;

    float* feats[4] = {abuf, bbuf, cbuf, dbuf};

    knn_kernel<<<BB, 512, 0, stream>>>(x, 4, idxb);
    conv1_kernel<<<BB * 32, 256, 0, stream>>>(x, idxb, c1w1, c1b1, c1w2, c1b2, abuf);

    for (int L = 0; L < 3; ++L) {
        const float* fin = feats[L];
        float* fout = feats[L + 1];
        knn_kernel<<<BB, 512, 0, stream>>>(fin, 192, idxb);
        wprep_kernel<<<(192 * 512) / 256, 256, 0, stream>>>(cw1[L], wcat);
        for (int ch = 0; ch < nchunks; ++ch) {
            const size_t roff = (size_t)ch * CB * NN;
            pq_gemm_kernel<<<CB * 32, 256, 0, stream>>>(fin + roff * 192, wcat, pqbuf);
            conv234e_kernel<<<CB * 32, 256, 0, stream>>>(pqbuf, idxb + roff * KNNK,
                                                         cw2[L], cb1[L], cb2[L],
                                                         fout + roff * 192);
        }
    }

    nn12_kernel<<<BB * 32, 256, 0, stream>>>(x, abuf, bbuf, cbuf, dbuf, nn1w, nn1b, nn2w, nn2b, partials);
    pool_reduce_kernel<<<BB, 192, 0, stream>>>(partials, pooledL);
    head_kernel<<<BB, 128, 0, stream>>>(pooledL, nn3w, nn3b, nn4w, nn4b, out);
}

// Round 3
// 2795.813 us; speedup vs baseline: 4.2352x; 1.4168x over previous
//
#include <hip/hip_runtime.h>

#define BB 128
#define NN 512
#define KNNK 4

__device__ __forceinline__ float lrelu(float v) { return v > 0.0f ? v : 0.01f * v; }

// ---------------------------------------------------------------- kNN
__global__ __launch_bounds__(512)
void knn_kernel(const float* __restrict__ feat, int ldf, int* __restrict__ idx_out) {
    __shared__ float px[NN], py[NN], pz[NN], sq[NN];
    const int b = blockIdx.x;
    const int i = threadIdx.x;
    const float* fb = feat + (size_t)b * NN * ldf;
    const float x = fb[(size_t)i * ldf + 0];
    const float y = fb[(size_t)i * ldf + 1];
    const float z = fb[(size_t)i * ldf + 2];
    px[i] = x; py[i] = y; pz[i] = z;
    const float s = x * x + y * y + z * z;
    sq[i] = s;
    __syncthreads();
    float bd0 = 3.4e38f, bd1 = 3.4e38f, bd2 = 3.4e38f, bd3 = 3.4e38f;
    int bj0 = 0, bj1 = 0, bj2 = 0, bj3 = 0;
    for (int j = 0; j < NN; j++) {
        const float d2 = s + sq[j] - 2.0f * (x * px[j] + y * py[j] + z * pz[j]);
        if (j != i && d2 < bd3) {
            if (d2 < bd2) {
                bd3 = bd2; bj3 = bj2;
                if (d2 < bd1) {
                    bd2 = bd1; bj2 = bj1;
                    if (d2 < bd0) { bd1 = bd0; bj1 = bj0; bd0 = d2; bj0 = j; }
                    else { bd1 = d2; bj1 = j; }
                } else { bd2 = d2; bj2 = j; }
            } else { bd3 = d2; bj3 = j; }
        }
    }
    int* ip = idx_out + ((size_t)b * NN + i) * KNNK;
    ip[0] = bj0; ip[1] = bj1; ip[2] = bj2; ip[3] = bj3;
}

// ---------------------------------------------------------------- conv1 (unchanged)
__global__ __launch_bounds__(256, 2)
void conv1_kernel(const float* __restrict__ X,
                  const int* __restrict__ nidx,
                  const float* __restrict__ W1, const float* __restrict__ b1,
                  const float* __restrict__ W2, const float* __restrict__ b2,
                  float* __restrict__ out)
{
    __shared__ float E[8][64];
    __shared__ float W1s[8][96];
    __shared__ float h1t[96][64];
    __shared__ float W2t[32][192];
    __shared__ float b1s[96], b2s[192];

    const int t = threadIdx.x;
    const int b = blockIdx.x >> 5;
    const int nb = (blockIdx.x & 31) << 4;
    const float* Xb = X + (size_t)b * NN * 4;

    for (int i = t; i < 8 * 96; i += 256) W1s[i / 96][i % 96] = W1[i];
    if (t < 96) b1s[t] = b1[t];
    if (t < 192) b2s[t] = b2[t];

    if (t < 64) {
        const int e = t;
        const int node = nb + (e >> 2);
        const int j = nidx[((size_t)b * NN + node) * KNNK + (e & 3)];
        const float4 xi = *(const float4*)(Xb + (size_t)node * 4);
        const float4 xj = *(const float4*)(Xb + (size_t)j * 4);
        E[0][e] = xi.x; E[1][e] = xi.y; E[2][e] = xi.z; E[3][e] = xi.w;
        E[4][e] = xj.x - xi.x; E[5][e] = xj.y - xi.y; E[6][e] = xj.z - xi.z; E[7][e] = xj.w - xi.w;
    }
    __syncthreads();

    const int rg = t & 15;
    {   // GEMM1
        const int cg = t >> 4;
        float acc[4][6];
#pragma unroll
        for (int r = 0; r < 4; r++)
#pragma unroll
            for (int c = 0; c < 6; c++) acc[r][c] = 0.0f;
#pragma unroll
        for (int k = 0; k < 8; k++) {
            const float4 e4 = *(const float4*)&E[k][rg * 4];
            const float er[4] = {e4.x, e4.y, e4.z, e4.w};
            float wc[6];
#pragma unroll
            for (int c = 0; c < 6; c++) wc[c] = W1s[k][cg * 6 + c];
#pragma unroll
            for (int r = 0; r < 4; r++)
#pragma unroll
                for (int c = 0; c < 6; c++) acc[r][c] += er[r] * wc[c];
        }
#pragma unroll
        for (int c = 0; c < 6; c++) {
            const int col = cg * 6 + c;
            const float bias = b1s[col];
#pragma unroll
            for (int r = 0; r < 4; r++) h1t[col][rg * 4 + r] = lrelu(acc[r][c] + bias);
        }
    }
    __syncthreads();

    {   // GEMM2
        const int cg = t >> 4;
        float acc[4][12];
#pragma unroll
        for (int r = 0; r < 4; r++)
#pragma unroll
            for (int c = 0; c < 12; c++) acc[r][c] = 0.0f;
        for (int kt = 0; kt < 3; kt++) {
            for (int i = t; i < 32 * 192; i += 256)
                W2t[i / 192][i % 192] = W2[(size_t)(kt * 32 + i / 192) * 192 + i % 192];
            __syncthreads();
#pragma unroll
            for (int kk = 0; kk < 32; kk++) {
                const int k = kt * 32 + kk;
                const float4 e4 = *(const float4*)&h1t[k][rg * 4];
                const float er[4] = {e4.x, e4.y, e4.z, e4.w};
                float wc[12];
#pragma unroll
                for (int c = 0; c < 12; c += 4) {
                    const float4 w4 = *(const float4*)&W2t[kk][cg * 12 + c];
                    wc[c] = w4.x; wc[c + 1] = w4.y; wc[c + 2] = w4.z; wc[c + 3] = w4.w;
                }
#pragma unroll
                for (int r = 0; r < 4; r++)
#pragma unroll
                    for (int c = 0; c < 12; c++) acc[r][c] += er[r] * wc[c];
            }
            __syncthreads();
        }
        const int node = nb + rg;
        float res[12];
#pragma unroll
        for (int c = 0; c < 12; c++) {
            const float bias = b2s[cg * 12 + c];
            res[c] = lrelu(acc[0][c] + bias) + lrelu(acc[1][c] + bias)
                   + lrelu(acc[2][c] + bias) + lrelu(acc[3][c] + bias);
        }
        float* op = out + ((size_t)b * NN + node) * 192 + cg * 12;
#pragma unroll
        for (int c = 0; c < 12; c += 4) {
            float4 o; o.x = res[c]; o.y = res[c + 1]; o.z = res[c + 2]; o.w = res[c + 3];
            *(float4*)(op + c) = o;
        }
    }
}

// ---------------------------------------------------------------- weight prep
__global__ void wprep_kernel(const float* __restrict__ W1, float* __restrict__ Wcat) {
    const int idx = blockIdx.x * 256 + threadIdx.x;   // 192*512
    const int k = idx >> 9;
    const int c = idx & 511;
    float v = 0.0f;
    if (c < 252) v = W1[(size_t)k * 252 + c] - W1[(size_t)(192 + k) * 252 + c];
    else if (c >= 256 && c < 508) v = W1[(size_t)(192 + k) * 252 + (c - 256)];
    Wcat[idx] = v;
}

// ---------------------------------------------------------------- PQ node GEMM
__global__ __launch_bounds__(256, 4)
void pq_gemm_kernel(const float* __restrict__ X,
                    const float* __restrict__ Wcat,
                    float* __restrict__ PQ)
{
    __shared__ float Xt[16][68];
    __shared__ float Wt[16][128];
    const int t = threadIdx.x;
    const int m0 = (blockIdx.x >> 2) << 6;
    const int n0 = (blockIdx.x & 3) << 7;

    const int rg = t & 15, cg = t >> 4;
    const int sm = t >> 2;
    const int skq = (t & 3) << 2;

    const int q0 = t, q1 = t + 256;
    const int kkA = q0 >> 5, c4A = (q0 & 31) << 2;
    const int kkB = q1 >> 5, c4B = (q1 & 31) << 2;

    float acc[4][8];
#pragma unroll
    for (int r = 0; r < 4; r++)
#pragma unroll
        for (int c = 0; c < 8; c++) acc[r][c] = 0.0f;

    for (int kt = 0; kt < 12; ++kt) {
        const int k0 = kt << 4;
        const float4 xv = *(const float4*)&X[(size_t)(m0 + sm) * 192 + k0 + skq];
        Xt[skq + 0][sm] = xv.x;
        Xt[skq + 1][sm] = xv.y;
        Xt[skq + 2][sm] = xv.z;
        Xt[skq + 3][sm] = xv.w;
        *(float4*)&Wt[kkA][c4A] = *(const float4*)&Wcat[(size_t)(k0 + kkA) * 512 + n0 + c4A];
        *(float4*)&Wt[kkB][c4B] = *(const float4*)&Wcat[(size_t)(k0 + kkB) * 512 + n0 + c4B];
        __syncthreads();
#pragma unroll
        for (int kk = 0; kk < 16; ++kk) {
            const float4 x4 = *(const float4*)&Xt[kk][rg * 4];
            const float4 w0 = *(const float4*)&Wt[kk][cg * 8];
            const float4 w1 = *(const float4*)&Wt[kk][cg * 8 + 4];
            const float xr[4] = {x4.x, x4.y, x4.z, x4.w};
            const float wc[8] = {w0.x, w0.y, w0.z, w0.w, w1.x, w1.y, w1.z, w1.w};
#pragma unroll
            for (int r = 0; r < 4; r++)
#pragma unroll
                for (int c = 0; c < 8; c++) acc[r][c] += xr[r] * wc[c];
        }
        __syncthreads();
    }
#pragma unroll
    for (int r = 0; r < 4; r++) {
        float* op = PQ + (size_t)(m0 + rg * 4 + r) * 512 + n0 + cg * 8;
        float4 o0; o0.x = acc[r][0]; o0.y = acc[r][1]; o0.z = acc[r][2]; o0.w = acc[r][3];
        float4 o1; o1.x = acc[r][4]; o1.y = acc[r][5]; o1.z = acc[r][6]; o1.w = acc[r][7];
        *(float4*)op = o0;
        *(float4*)(op + 4) = o1;
    }
}

// ---------------------------------------------------------------- conv2/3/4 edge phase
__global__ __launch_bounds__(256, 4)
void conv234e_kernel(const float* __restrict__ PQ,
                     const int* __restrict__ nidx,
                     const float* __restrict__ W2,
                     const float* __restrict__ b1,
                     const float* __restrict__ b2,
                     float* __restrict__ out)
{
    __shared__ float h1c[16][64];
    __shared__ float Wt[16][192];
    __shared__ float b1s[256];
    __shared__ float b2s[192];

    const int t = threadIdx.x;
    const int nodebase = (blockIdx.x >> 5) << 9;
    const int nb = (blockIdx.x & 31) << 4;

    b1s[t] = (t < 252) ? b1[t] : 0.0f;
    if (t < 192) b2s[t] = b2[t];

    const int m = t & 15;
    const int ks = t >> 4;

    const int4 jj = *(const int4*)&nidx[(size_t)(nodebase + nb + m) * 4];
    const float* Prow = PQ + (size_t)(nodebase + nb + m) * 512;
    const float* Q0 = PQ + (size_t)(nodebase + jj.x) * 512 + 256;
    const float* Q1 = PQ + (size_t)(nodebase + jj.y) * 512 + 256;
    const float* Q2 = PQ + (size_t)(nodebase + jj.z) * 512 + 256;
    const float* Q3 = PQ + (size_t)(nodebase + jj.w) * 512 + 256;

    const int qa = t, qb = t + 256, qc = t + 512;
    const int kka = qa / 48, ca = (qa % 48) << 2;
    const int kkb = qb / 48, cb = (qb % 48) << 2;
    const int kkc = qc / 48, cc = (qc % 48) << 2;

    float acc[4][12];
#pragma unroll
    for (int r = 0; r < 4; r++)
#pragma unroll
        for (int c = 0; c < 12; c++) acc[r][c] = 0.0f;

    __syncthreads();

    const float4 zero4 = {0.0f, 0.0f, 0.0f, 0.0f};
    for (int kt = 0; kt < 16; ++kt) {
        const int k0 = kt << 4;
        {
            const int k = k0 + ks;
            const float pv = Prow[k] + b1s[k];
            float4 h;
            h.x = lrelu(pv + Q0[k]);
            h.y = lrelu(pv + Q1[k]);
            h.z = lrelu(pv + Q2[k]);
            h.w = lrelu(pv + Q3[k]);
            *(float4*)&h1c[ks][m * 4] = h;
        }
        {
            const int ra = k0 + kka, rb = k0 + kkb, rc = k0 + kkc;
            *(float4*)&Wt[kka][ca] = (ra < 252) ? *(const float4*)&W2[(size_t)ra * 192 + ca] : zero4;
            *(float4*)&Wt[kkb][cb] = (rb < 252) ? *(const float4*)&W2[(size_t)rb * 192 + cb] : zero4;
            *(float4*)&Wt[kkc][cc] = (rc < 252) ? *(const float4*)&W2[(size_t)rc * 192 + cc] : zero4;
        }
        __syncthreads();
#pragma unroll
        for (int kk = 0; kk < 16; ++kk) {
            const float4 h4 = *(const float4*)&h1c[kk][m * 4];
            const float4 w0 = *(const float4*)&Wt[kk][ks * 12];
            const float4 w1 = *(const float4*)&Wt[kk][ks * 12 + 4];
            const float4 w2 = *(const float4*)&Wt[kk][ks * 12 + 8];
            const float hr[4] = {h4.x, h4.y, h4.z, h4.w};
            const float wc[12] = {w0.x, w0.y, w0.z, w0.w, w1.x, w1.y, w1.z, w1.w, w2.x, w2.y, w2.z, w2.w};
#pragma unroll
            for (int r = 0; r < 4; r++)
#pragma unroll
                for (int c = 0; c < 12; c++) acc[r][c] += hr[r] * wc[c];
        }
        __syncthreads();
    }
    float res[12];
#pragma unroll
    for (int c = 0; c < 12; c++) {
        const float bias = b2s[ks * 12 + c];
        res[c] = lrelu(acc[0][c] + bias) + lrelu(acc[1][c] + bias)
               + lrelu(acc[2][c] + bias) + lrelu(acc[3][c] + bias);
    }
    float* op = out + (size_t)(nodebase + nb + m) * 192 + ks * 12;
#pragma unroll
    for (int c = 0; c < 12; c += 4) {
        float4 o; o.x = res[c]; o.y = res[c + 1]; o.z = res[c + 2]; o.w = res[c + 3];
        *(float4*)(op + c) = o;
    }
}

// ---------------------------------------------------------------- nn1 GEMM
// h1[rows][256] = lrelu([x|a|b|c|d] @ W1 + b1), cols>=252 pad to 0.
// 64 rows x 128 cols per block; grid = rows/64 * 2.
__global__ __launch_bounds__(256, 4)
void nn1_gemm_kernel(const float* __restrict__ x,    // [rows][4]
                     const float* __restrict__ a,
                     const float* __restrict__ bf,
                     const float* __restrict__ cf,
                     const float* __restrict__ df,   // [rows][192] each
                     const float* __restrict__ W1,   // [772][252]
                     const float* __restrict__ b1,   // [252]
                     float* __restrict__ h1)         // [rows][256]
{
    __shared__ float Xt[16][68];
    __shared__ float Wt[16][128];
    __shared__ float b1s[128];

    const int t = threadIdx.x;
    const int m0 = (blockIdx.x >> 1) << 6;
    const int n0 = (blockIdx.x & 1) << 7;
    const int rg = t & 15, cg = t >> 4;
    const int sm = t >> 2, skq = (t & 3) << 2;
    const int kkA = t >> 5, c4A = (t & 31) << 2;   // W stage rows kkA and kkA+8

    const float4 zero4 = {0.0f, 0.0f, 0.0f, 0.0f};

    if (t < 128) { const int col = n0 + t; b1s[t] = (col < 252) ? b1[col] : 0.0f; }

    float acc[4][8];
#pragma unroll
    for (int r = 0; r < 4; r++)
#pragma unroll
        for (int c = 0; c < 8; c++) acc[r][c] = 0.0f;

    // ---- x segment (K=4, W1 rows 0..3)
    if (t < 64) {
        const float4 xv = *(const float4*)&x[(size_t)(m0 + t) * 4];
        Xt[0][t] = xv.x; Xt[1][t] = xv.y; Xt[2][t] = xv.z; Xt[3][t] = xv.w;
    }
    if (t < 128) {
        const int kk = t >> 5, c4 = (t & 31) << 2;
        const int col = n0 + c4;
        *(float4*)&Wt[kk][c4] = (col <= 248) ? *(const float4*)&W1[(size_t)kk * 252 + col] : zero4;
    }
    __syncthreads();
#pragma unroll
    for (int kk = 0; kk < 4; ++kk) {
        const float4 x4 = *(const float4*)&Xt[kk][rg * 4];
        const float4 w0 = *(const float4*)&Wt[kk][cg * 8];
        const float4 w1 = *(const float4*)&Wt[kk][cg * 8 + 4];
        const float xr[4] = {x4.x, x4.y, x4.z, x4.w};
        const float wc[8] = {w0.x, w0.y, w0.z, w0.w, w1.x, w1.y, w1.z, w1.w};
#pragma unroll
        for (int r = 0; r < 4; r++)
#pragma unroll
            for (int c = 0; c < 8; c++) acc[r][c] += xr[r] * wc[c];
    }
    __syncthreads();

    // ---- a/b/c/d segments (K=192 each, W1 rows 4+seg*192 ...)
    const float* srcs[4] = {a, bf, cf, df};
#pragma unroll 1
    for (int seg = 0; seg < 4; ++seg) {
        const float* sp = srcs[seg];
        const int wbase = 4 + seg * 192;
        for (int kt = 0; kt < 12; ++kt) {
            const int k0 = kt << 4;
            const float4 xv = *(const float4*)&sp[(size_t)(m0 + sm) * 192 + k0 + skq];
            Xt[skq + 0][sm] = xv.x;
            Xt[skq + 1][sm] = xv.y;
            Xt[skq + 2][sm] = xv.z;
            Xt[skq + 3][sm] = xv.w;
            {
                const int col = n0 + c4A;
                const bool ok = (col <= 248);
                *(float4*)&Wt[kkA][c4A] =
                    ok ? *(const float4*)&W1[(size_t)(wbase + k0 + kkA) * 252 + col] : zero4;
                *(float4*)&Wt[kkA + 8][c4A] =
                    ok ? *(const float4*)&W1[(size_t)(wbase + k0 + kkA + 8) * 252 + col] : zero4;
            }
            __syncthreads();
#pragma unroll
            for (int kk = 0; kk < 16; ++kk) {
                const float4 x4 = *(const float4*)&Xt[kk][rg * 4];
                const float4 w0 = *(const float4*)&Wt[kk][cg * 8];
                const float4 w1 = *(const float4*)&Wt[kk][cg * 8 + 4];
                const float xr[4] = {x4.x, x4.y, x4.z, x4.w};
                const float wc[8] = {w0.x, w0.y, w0.z, w0.w, w1.x, w1.y, w1.z, w1.w};
#pragma unroll
                for (int r = 0; r < 4; r++)
#pragma unroll
                    for (int c = 0; c < 8; c++) acc[r][c] += xr[r] * wc[c];
            }
            __syncthreads();
        }
    }

    // ---- epilogue: bias + lrelu, store h1
#pragma unroll
    for (int r = 0; r < 4; r++) {
        float* op = h1 + (size_t)(m0 + rg * 4 + r) * 256 + n0 + cg * 8;
        float4 o0, o1;
        o0.x = lrelu(acc[r][0] + b1s[cg * 8 + 0]);
        o0.y = lrelu(acc[r][1] + b1s[cg * 8 + 1]);
        o0.z = lrelu(acc[r][2] + b1s[cg * 8 + 2]);
        o0.w = lrelu(acc[r][3] + b1s[cg * 8 + 3]);
        o1.x = lrelu(acc[r][4] + b1s[cg * 8 + 4]);
        o1.y = lrelu(acc[r][5] + b1s[cg * 8 + 5]);
        o1.z = lrelu(acc[r][6] + b1s[cg * 8 + 6]);
        o1.w = lrelu(acc[r][7] + b1s[cg * 8 + 7]);
        *(float4*)op = o0;
        *(float4*)(op + 4) = o1;
    }
}

// ---------------------------------------------------------------- nn2 GEMM + fused pooling
// h2 = h1 @ W2 + b2 (no act); per-64-row-block max/min/sum -> partials [B][8][3][192]
__global__ __launch_bounds__(256, 4)
void nn2pool_kernel(const float* __restrict__ h1,   // [rows][256]
                    const float* __restrict__ W2,   // [252][192]
                    const float* __restrict__ b2,   // [192]
                    int grow0,                      // global row offset of chunk
                    float* __restrict__ partials)
{
    __shared__ float Ht[16][68];
    __shared__ float Wt[16][192];
    __shared__ float b2s[192];

    const int t = threadIdx.x;
    const int m0 = blockIdx.x << 6;
    const int rg = t & 15, cg = t >> 4;
    const int sm = t >> 2, skq = (t & 3) << 2;
    const int kka = t / 48, ca = (t % 48) << 2;
    const int kkb = (t + 256) / 48, cb = ((t + 256) % 48) << 2;
    const int kkc = (t + 512) / 48, cc = ((t + 512) % 48) << 2;

    if (t < 192) b2s[t] = b2[t];

    float acc[4][12];
#pragma unroll
    for (int r = 0; r < 4; r++)
#pragma unroll
        for (int c = 0; c < 12; c++) acc[r][c] = 0.0f;

    const float4 zero4 = {0.0f, 0.0f, 0.0f, 0.0f};
    for (int kt = 0; kt < 16; ++kt) {
        const int k0 = kt << 4;
        const float4 hv = *(const float4*)&h1[(size_t)(m0 + sm) * 256 + k0 + skq];
        Ht[skq + 0][sm] = hv.x;
        Ht[skq + 1][sm] = hv.y;
        Ht[skq + 2][sm] = hv.z;
        Ht[skq + 3][sm] = hv.w;
        {
            const int ra = k0 + kka, rb = k0 + kkb, rc = k0 + kkc;
            *(float4*)&Wt[kka][ca] = (ra < 252) ? *(const float4*)&W2[(size_t)ra * 192 + ca] : zero4;
            *(float4*)&Wt[kkb][cb] = (rb < 252) ? *(const float4*)&W2[(size_t)rb * 192 + cb] : zero4;
            *(float4*)&Wt[kkc][cc] = (rc < 252) ? *(const float4*)&W2[(size_t)rc * 192 + cc] : zero4;
        }
        __syncthreads();
#pragma unroll
        for (int kk = 0; kk < 16; ++kk) {
            const float4 h4 = *(const float4*)&Ht[kk][rg * 4];
            const float4 w0 = *(const float4*)&Wt[kk][cg * 12];
            const float4 w1 = *(const float4*)&Wt[kk][cg * 12 + 4];
            const float4 w2 = *(const float4*)&Wt[kk][cg * 12 + 8];
            const float hr[4] = {h4.x, h4.y, h4.z, h4.w};
            const float wc[12] = {w0.x, w0.y, w0.z, w0.w, w1.x, w1.y, w1.z, w1.w, w2.x, w2.y, w2.z, w2.w};
#pragma unroll
            for (int r = 0; r < 4; r++)
#pragma unroll
                for (int c = 0; c < 12; c++) acc[r][c] += hr[r] * wc[c];
        }
        __syncthreads();
    }

    // bias + per-thread (4-row) reduce, then 16-lane shuffle tree across row-groups
    float vmx[12], vmn[12], vsm[12];
#pragma unroll
    for (int c = 0; c < 12; c++) {
        const float bias = b2s[cg * 12 + c];
        const float v0 = acc[0][c] + bias;
        const float v1 = acc[1][c] + bias;
        const float v2 = acc[2][c] + bias;
        const float v3 = acc[3][c] + bias;
        vmx[c] = fmaxf(fmaxf(v0, v1), fmaxf(v2, v3));
        vmn[c] = fminf(fminf(v0, v1), fminf(v2, v3));
        vsm[c] = (v0 + v1) + (v2 + v3);
    }
#pragma unroll
    for (int s = 1; s < 16; s <<= 1) {
#pragma unroll
        for (int c = 0; c < 12; c++) {
            vmx[c] = fmaxf(vmx[c], __shfl_xor(vmx[c], s));
            vmn[c] = fminf(vmn[c], __shfl_xor(vmn[c], s));
            vsm[c] += __shfl_xor(vsm[c], s);
        }
    }
    if ((t & 15) == 0) {
        const int grow = grow0 + m0;
        const int b = grow >> 9;
        const int rb8 = (grow & 511) >> 6;
        float* pp = partials + (((size_t)b * 8 + rb8) * 3) * 192;
#pragma unroll
        for (int c = 0; c < 12; c++) {
            const int col = cg * 12 + c;
            pp[col] = vmx[c];
            pp[192 + col] = vmn[c];
            pp[384 + col] = vsm[c];
        }
    }
}

// ---------------------------------------------------------------- pool reduce (8 partials)
__global__ void pool_reduce_kernel(const float* __restrict__ partials, float* __restrict__ pooledL) {
    const int b = blockIdx.x, c = threadIdx.x;
    float mx = -3.4e38f, mn = 3.4e38f, sm = 0.0f;
    for (int blk = 0; blk < 8; blk++) {
        const float* pp = partials + ((size_t)b * 8 + blk) * 3 * 192;
        mx = fmaxf(mx, pp[c]);
        mn = fminf(mn, pp[192 + c]);
        sm += pp[384 + c];
    }
    float* o = pooledL + (size_t)b * 768;
    o[c] = lrelu(mx);
    o[192 + c] = lrelu(mn);
    o[384 + c] = lrelu(sm);
    o[576 + c] = lrelu(sm * (1.0f / 512.0f));
}

// ---------------------------------------------------------------- head
__global__ __launch_bounds__(128)
void head_kernel(const float* __restrict__ pooledL,
                 const float* __restrict__ W3, const float* __restrict__ b3,
                 const float* __restrict__ W4, const float* __restrict__ b4,
                 float* __restrict__ out) {
    __shared__ float pl[768];
    __shared__ float h3[96];
    const int b = blockIdx.x, t = threadIdx.x;
    for (int i = t; i < 768; i += 128) pl[i] = pooledL[(size_t)b * 768 + i];
    __syncthreads();
    if (t < 96) {
        float acc = b3[t];
        for (int k = 0; k < 768; k++) acc += pl[k] * W3[(size_t)k * 96 + t];
        h3[t] = lrelu(acc);
    }
    __syncthreads();
    if (t == 0) {
        float s2 = b4[0];
        for (int o = 0; o < 96; o++) s2 += h3[o] * W4[o];
        out[b] = s2;
    }
}

// ---------------------------------------------------------------- launch
extern "C" void kernel_launch(void* const* d_in, const int* in_sizes, int n_in,
                              void* d_out, int out_size, void* d_ws, size_t ws_size,
                              hipStream_t stream) {
    const float* x    = (const float*)d_in[0];
    const float* c1w1 = (const float*)d_in[1];
    const float* c1b1 = (const float*)d_in[2];
    const float* c1w2 = (const float*)d_in[3];
    const float* c1b2 = (const float*)d_in[4];
    const float* cw1[3] = {(const float*)d_in[5], (const float*)d_in[9],  (const float*)d_in[13]};
    const float* cb1[3] = {(const float*)d_in[6], (const float*)d_in[10], (const float*)d_in[14]};
    const float* cw2[3] = {(const float*)d_in[7], (const float*)d_in[11], (const float*)d_in[15]};
    const float* cb2[3] = {(const float*)d_in[8], (const float*)d_in[12], (const float*)d_in[16]};
    const float* nn1w = (const float*)d_in[17];
    const float* nn1b = (const float*)d_in[18];
    const float* nn2w = (const float*)d_in[19];
    const float* nn2b = (const float*)d_in[20];
    const float* nn3w = (const float*)d_in[21];
    const float* nn3b = (const float*)d_in[22];
    const float* nn4w = (const float*)d_in[23];
    const float* nn4b = (const float*)d_in[24];
    float* out = (float*)d_out;

    // workspace layout (floats)
    const size_t featN = (size_t)BB * NN * 192;
    const size_t idx_f = (size_t)BB * NN * KNNK;        // ints
    const size_t part_f = (size_t)BB * 8 * 3 * 192;
    const size_t pool_f = (size_t)BB * 768;
    const size_t wcat_f = (size_t)192 * 512;

    float* abuf = (float*)d_ws;
    float* bbuf = abuf + featN;
    float* cbuf = bbuf + featN;
    float* dbuf = cbuf + featN;
    int*   idxb = (int*)(dbuf + featN);
    float* partials = (float*)(idxb + idx_f);
    float* pooledL = partials + part_f;
    float* wcat = pooledL + pool_f;
    float* pqbuf = wcat + wcat_f;

    // pick largest batch-chunk for the PQ/h1 buffer that fits ws
    int CB = BB;
    while (CB > 1) {
        const size_t need = (4 * featN + idx_f + part_f + pool_f + wcat_f +
                             (size_t)CB * NN * 512) * 4;
        if (need <= ws_size) break;
        CB >>= 1;
    }
    const int nchunks = BB / CB;

    float* feats[4] = {abuf, bbuf, cbuf, dbuf};

    knn_kernel<<<BB, 512, 0, stream>>>(x, 4, idxb);
    conv1_kernel<<<BB * 32, 256, 0, stream>>>(x, idxb, c1w1, c1b1, c1w2, c1b2, abuf);

    for (int L = 0; L < 3; ++L) {
        const float* fin = feats[L];
        float* fout = feats[L + 1];
        knn_kernel<<<BB, 512, 0, stream>>>(fin, 192, idxb);
        wprep_kernel<<<(192 * 512) / 256, 256, 0, stream>>>(cw1[L], wcat);
        for (int ch = 0; ch < nchunks; ++ch) {
            const size_t roff = (size_t)ch * CB * NN;
            pq_gemm_kernel<<<CB * 32, 256, 0, stream>>>(fin + roff * 192, wcat, pqbuf);
            conv234e_kernel<<<CB * 32, 256, 0, stream>>>(pqbuf, idxb + roff * KNNK,
                                                         cw2[L], cb1[L], cb2[L],
                                                         fout + roff * 192);
        }
    }

    // nn1 + nn2 + pooling (h1 chunk reuses the pqbuf region)
    float* h1buf = pqbuf;
    for (int ch = 0; ch < nchunks; ++ch) {
        const size_t roff = (size_t)ch * CB * NN;
        nn1_gemm_kernel<<<CB * 16, 256, 0, stream>>>(x + roff * 4,
                                                     abuf + roff * 192, bbuf + roff * 192,
                                                     cbuf + roff * 192, dbuf + roff * 192,
                                                     nn1w, nn1b, h1buf);
        nn2pool_kernel<<<CB * 8, 256, 0, stream>>>(h1buf, nn2w, nn2b, (int)roff, partials);
    }
    pool_reduce_kernel<<<BB, 192, 0, stream>>>(partials, pooledL);
    head_kernel<<<BB, 128, 0, stream>>>(pooledL, nn3w, nn3b, nn4w, nn4b, out);
}